// Round 5
// baseline (679.353 us; speedup 1.0000x reference)
//
#include <hip/hip_runtime.h>
#include <math.h>

#define NB 4
#define NCX 16
#define NC1 16
#define NCA 8
#define NN 1024
#define ND 64
#define NL 64
#define NCG 4          // channel groups for k_smean partials
#define HSTRIDE 1028   // halfwords; row step = 2056 B -> 8-bank shift per 4 rows,
                       // 2-way (free) on both 2B stores and b64 reads; 8B-aligned

typedef __attribute__((ext_vector_type(8))) short bf16x8;
typedef __attribute__((ext_vector_type(4))) float f32x4;
typedef _Float16 h4 __attribute__((ext_vector_type(4)));
typedef unsigned short u16;
typedef unsigned int u32;

// RNE float -> bf16 bits
__device__ __forceinline__ u16 f2b(float f) {
    u32 u = __float_as_uint(f);
    return (u16)((u + 0x7FFFu + ((u >> 16) & 1u)) >> 16);
}

// load 8 consecutive floats, convert to a bf16 MFMA fragment
__device__ __forceinline__ bf16x8 cvt8(const float* __restrict__ p) {
    float4 a = *(const float4*)p;
    float4 b = *(const float4*)(p + 4);
    bf16x8 r;
    r[0] = (short)f2b(a.x); r[1] = (short)f2b(a.y);
    r[2] = (short)f2b(a.z); r[3] = (short)f2b(a.w);
    r[4] = (short)f2b(b.x); r[5] = (short)f2b(b.y);
    r[6] = (short)f2b(b.z); r[7] = (short)f2b(b.w);
    return r;
}

__device__ __forceinline__ float sigm(float z) {
    return 1.0f / (1.0f + __expf(-z));
}

// ---------------------------------------------------------------------------
// K0: generic fp32 -> bf16 (8 elems/thread). Used for x->xb and mask->maskb.
// ---------------------------------------------------------------------------
__global__ __launch_bounds__(256) void k_cvt(const float* __restrict__ src,
                                             u16* __restrict__ dst) {
    int id = blockIdx.x * 256 + threadIdx.x;
    const float4* x4 = (const float4*)src;
    float4 a = x4[2 * id];
    float4 b = x4[2 * id + 1];
    union { u16 u[8]; uint4 v; } o;
    o.u[0] = f2b(a.x); o.u[1] = f2b(a.y); o.u[2] = f2b(a.z); o.u[3] = f2b(a.w);
    o.u[4] = f2b(b.x); o.u[5] = f2b(b.y); o.u[6] = f2b(b.z); o.u[7] = f2b(b.w);
    ((uint4*)dst)[id] = o.v;
}

// ---------------------------------------------------------------------------
// K1: meanA[b,i,j] = (1/8) * sum_c A[b,c,i,j]
// ---------------------------------------------------------------------------
__global__ __launch_bounds__(256) void k_meanA(const float* __restrict__ A,
                                               float* __restrict__ meanA) {
    int id = blockIdx.x * 256 + threadIdx.x;
    int b  = id >> 18;                         // N*N/4 = 262144
    int e  = id & 262143;
    const float4* A4 = (const float4*)A;
    float4 s = A4[(size_t)(b * NCA) * 262144 + e];
#pragma unroll
    for (int c = 1; c < NCA; ++c) {
        float4 v = A4[(size_t)(b * NCA + c) * 262144 + e];
        s.x += v.x; s.y += v.y; s.z += v.z; s.w += v.w;
    }
    s.x *= 0.125f; s.y *= 0.125f; s.z *= 0.125f; s.w *= 0.125f;
    ((float4*)meanA)[id] = s;
}

// ---------------------------------------------------------------------------
// K2: partial softmax-sums, 512-thread blocks for 4-resident/CU.
// Block (i-tile 8, b, cg): 8 waves; wave w computes cols [w*128,(w+1)*128)
// (8 MFMA tiles over 16 rows, lower 8 rows kept) then softmaxes row i0+w.
// Logits stored fp16 in LDS (|l|<~120, ulp 0.03 -> S error <2% rel, ~0 abs).
// Spart[cg][b][i][j] = sum_{c in group} softmax_j(x_i . x_j).
// ---------------------------------------------------------------------------
__global__ __launch_bounds__(512, 8) void k_smean5(const u16* __restrict__ xb,
                                                   float* __restrict__ Spart) {
    __shared__ _Float16 Lh[8 * HSTRIDE];   // 16.4 KB
    const int t  = threadIdx.x;
    const int w  = t >> 6;              // wave 0..7
    const int l  = t & 63;
    const int lm = l & 15;
    const int lq = l >> 4;
    const int i0 = blockIdx.x * 8;
    const int b  = blockIdx.y;
    const int cg = blockIdx.z;
    const int rb = lq * 4;              // C/D row base (keep rows < 8 only)

    float mean[16];
#pragma unroll
    for (int u = 0; u < 16; ++u) mean[u] = 0.f;

    const int arow = min(i0 + lm, NN - 1);   // rows >= 8 computed, discarded

    for (int c = cg * 4; c < cg * 4 + 4; ++c) {
        const u16* Xc = xb + (size_t)(b * NCX + c) * NN * ND;
        bf16x8 a0 = *(const bf16x8*)(Xc + arow * ND + lq * 8);
        bf16x8 a1 = *(const bf16x8*)(Xc + arow * ND + 32 + lq * 8);
#pragma unroll
        for (int tt = 0; tt < 8; ++tt) {
            int j0 = w * 128 + tt * 16;
            const u16* Bp = Xc + (j0 + lm) * ND;
            bf16x8 b0 = *(const bf16x8*)(Bp + lq * 8);
            bf16x8 b1 = *(const bf16x8*)(Bp + 32 + lq * 8);
            f32x4 acc = {0.f, 0.f, 0.f, 0.f};
            acc = __builtin_amdgcn_mfma_f32_16x16x32_bf16(a0, b0, acc, 0, 0, 0);
            acc = __builtin_amdgcn_mfma_f32_16x16x32_bf16(a1, b1, acc, 0, 0, 0);
            if (lq < 2) {                  // rows 0..7 of the tile
                int col = j0 + lm;
                Lh[(rb + 0) * HSTRIDE + col] = (_Float16)acc[0];
                Lh[(rb + 1) * HSTRIDE + col] = (_Float16)acc[1];
                Lh[(rb + 2) * HSTRIDE + col] = (_Float16)acc[2];
                Lh[(rb + 3) * HSTRIDE + col] = (_Float16)acc[3];
            }
        }
        __syncthreads();
        {   // softmax of row i0+w; lane l owns cols 4l + 256u (+k)
            const _Float16* Lp = &Lh[w * HSTRIDE];
            float v[16];
#pragma unroll
            for (int u = 0; u < 4; ++u) {
                h4 q = *(const h4*)&Lp[4 * l + 256 * u];
                v[4 * u + 0] = (float)q[0]; v[4 * u + 1] = (float)q[1];
                v[4 * u + 2] = (float)q[2]; v[4 * u + 3] = (float)q[3];
            }
            float m = v[0];
#pragma unroll
            for (int u = 1; u < 16; ++u) m = fmaxf(m, v[u]);
#pragma unroll
            for (int off = 32; off; off >>= 1) m = fmaxf(m, __shfl_xor(m, off, 64));
            float sum = 0.f;
#pragma unroll
            for (int u = 0; u < 16; ++u) { v[u] = __expf(v[u] - m); sum += v[u]; }
#pragma unroll
            for (int off = 32; off; off >>= 1) sum += __shfl_xor(sum, off, 64);
            float r = 1.0f / sum;
#pragma unroll
            for (int u = 0; u < 16; ++u) mean[u] = fmaf(v[u], r, mean[u]);
        }
        __syncthreads();   // before next channel overwrites Lh
    }
    float* Sp = Spart + (((size_t)(cg * NB + b)) * NN + (i0 + w)) * NN;
#pragma unroll
    for (int u = 0; u < 4; ++u) {
        float4 o;
        o.x = mean[4 * u + 0]; o.y = mean[4 * u + 1];
        o.z = mean[4 * u + 2]; o.w = mean[4 * u + 3];
        *(float4*)(Sp + 4 * l + 256 * u) = o;
    }
}

// ---------------------------------------------------------------------------
// K2b: Smean = (1/16) * (P0+P1+P2+P3)
// ---------------------------------------------------------------------------
__global__ __launch_bounds__(256) void k_sred(const float* __restrict__ Spart,
                                              float* __restrict__ Smean) {
    int id = blockIdx.x * 256 + threadIdx.x;   // float4 index over B*N*N/4
    int b  = id >> 18;
    int e  = id & 262143;
    const float4* P4 = (const float4*)Spart;
    float4 s = P4[(size_t)b * 262144 + e];
#pragma unroll
    for (int g = 1; g < NCG; ++g) {
        float4 v = P4[(size_t)(g * NB + b) * 262144 + e];
        s.x += v.x; s.y += v.y; s.z += v.z; s.w += v.w;
    }
    s.x *= 0.0625f; s.y *= 0.0625f; s.z *= 0.0625f; s.w *= 0.0625f;
    ((float4*)Smean)[id] = s;
}

// ---------------------------------------------------------------------------
// K3: mm via MFMA -> fp16 LDS -> per-wave-row epilogue, 512-thread blocks
// (4-resident/CU). A_out = meanA + 0.02*sigmoid(S*mm/sqrt(10)); top-5
// (tie -> lowest index); gather fp32 mask rows; max-reduce.
// ---------------------------------------------------------------------------
template <bool MB>
__global__ __launch_bounds__(512, 8) void k_final5(const float* __restrict__ mask,
                                                   const u16* __restrict__ maskb,
                                                   const float* __restrict__ Smean,
                                                   const float* __restrict__ meanA,
                                                   float* __restrict__ Aout,
                                                   float* __restrict__ maskUpd) {
    __shared__ _Float16 Lh[8 * HSTRIDE];   // 16.4 KB
    const int t  = threadIdx.x;
    const int w  = t >> 6;
    const int l  = t & 63;
    const int lm = l & 15;
    const int lq = l >> 4;
    const int i0 = blockIdx.x * 8;
    const int c1 = blockIdx.y;
    const int b  = blockIdx.z;
    const int rb = lq * 4;
    const int row = i0 + w;

    const float* mbase = mask + (size_t)(b * NC1 + c1) * NN * NL;
    const u16*   mbb   = maskb + (size_t)(b * NC1 + c1) * NN * NL;

    const int arow = min(i0 + lm, NN - 1);   // rows >= 8 computed, discarded
    bf16x8 a0, a1;
    if (MB) {
        a0 = *(const bf16x8*)(mbb + arow * NL + lq * 8);
        a1 = *(const bf16x8*)(mbb + arow * NL + 32 + lq * 8);
    } else {
        a0 = cvt8(mbase + arow * NL + lq * 8);
        a1 = cvt8(mbase + arow * NL + 32 + lq * 8);
    }
#pragma unroll
    for (int tt = 0; tt < 8; ++tt) {
        int j0 = w * 128 + tt * 16;
        bf16x8 b0, b1;
        if (MB) {
            const u16* Bp = mbb + (j0 + lm) * NL;
            b0 = *(const bf16x8*)(Bp + lq * 8);
            b1 = *(const bf16x8*)(Bp + 32 + lq * 8);
        } else {
            const float* Bp = mbase + (j0 + lm) * NL;
            b0 = cvt8(Bp + lq * 8);
            b1 = cvt8(Bp + 32 + lq * 8);
        }
        f32x4 acc = {0.f, 0.f, 0.f, 0.f};
        acc = __builtin_amdgcn_mfma_f32_16x16x32_bf16(a0, b0, acc, 0, 0, 0);
        acc = __builtin_amdgcn_mfma_f32_16x16x32_bf16(a1, b1, acc, 0, 0, 0);
        if (lq < 2) {
            int col = j0 + lm;
            Lh[(rb + 0) * HSTRIDE + col] = (_Float16)acc[0];
            Lh[(rb + 1) * HSTRIDE + col] = (_Float16)acc[1];
            Lh[(rb + 2) * HSTRIDE + col] = (_Float16)acc[2];
            Lh[(rb + 3) * HSTRIDE + col] = (_Float16)acc[3];
        }
    }
    __syncthreads();

    const _Float16* Lp = &Lh[w * HSTRIDE];
    const float* Sp = Smean + ((size_t)b * NN + row) * NN;
    const float* Mp = meanA + ((size_t)b * NN + row) * NN;
    float* Ap = Aout + ((size_t)(b * NC1 + c1) * NN + row) * NN;

    float lg[16];
#pragma unroll
    for (int u = 0; u < 4; ++u) {
        int j = 4 * l + 256 * u;
        h4 q = *(const h4*)&Lp[j];
        float4 S4 = *(const float4*)(Sp + j);
        float4 M4 = *(const float4*)(Mp + j);
        float4 o;
        o.x = M4.x + 0.02f * sigm(S4.x * (float)q[0] * 0.31622776601683794f);
        o.y = M4.y + 0.02f * sigm(S4.y * (float)q[1] * 0.31622776601683794f);
        o.z = M4.z + 0.02f * sigm(S4.z * (float)q[2] * 0.31622776601683794f);
        o.w = M4.w + 0.02f * sigm(S4.w * (float)q[3] * 0.31622776601683794f);
        *(float4*)(Ap + j) = o;
        lg[4 * u + 0] = o.x; lg[4 * u + 1] = o.y;
        lg[4 * u + 2] = o.z; lg[4 * u + 3] = o.w;
    }

    // top-5 (lane l's element k -> col j = 4l + 256*(k>>2) + (k&3);
    // ascending in k so strict > keeps the lowest index locally)
    int idxs[5];
#pragma unroll
    for (int p = 0; p < 5; ++p) {
        float bv = lg[0];
        int   bj = 4 * l;
#pragma unroll
        for (int k = 1; k < 16; ++k) {
            int j = 4 * l + 256 * (k >> 2) + (k & 3);
            if (lg[k] > bv) { bv = lg[k]; bj = j; }
        }
#pragma unroll
        for (int off = 32; off; off >>= 1) {
            float ov = __shfl_xor(bv, off, 64);
            int   oj = __shfl_xor(bj, off, 64);
            if (ov > bv || (ov == bv && oj < bj)) { bv = ov; bj = oj; }
        }
        idxs[p] = bj;
        const bool mine = ((bj & 255) >> 2) == l;
        const int  ck   = (bj >> 8) * 4 + (bj & 3);
#pragma unroll
        for (int k = 0; k < 16; ++k)
            lg[k] = (mine && k == ck) ? -INFINITY : lg[k];
    }
    float mx = mbase[(size_t)idxs[0] * NL + l];
#pragma unroll
    for (int p = 1; p < 5; ++p)
        mx = fmaxf(mx, mbase[(size_t)idxs[p] * NL + l]);
    maskUpd[((size_t)(b * NC1 + c1) * NN + row) * NL + l] = mx;
}

// ---------------------------------------------------------------------------
extern "C" void kernel_launch(void* const* d_in, const int* in_sizes, int n_in,
                              void* d_out, int out_size, void* d_ws, size_t ws_size,
                              hipStream_t stream) {
    const float* x    = (const float*)d_in[0];
    const float* A    = (const float*)d_in[1];
    const float* mask = (const float*)d_in[2];
    float* out     = (float*)d_out;
    float* Aout    = out;                                   // (B,C1,N,N)
    float* maskUpd = out + (size_t)NB * NC1 * NN * NN;      // (B,C1,N,L)
    float* meanA   = (float*)d_ws;                          // (B,N,N)  16.8 MB
    float* Smean   = meanA + (size_t)NB * NN * NN;          // (B,N,N)  16.8 MB
    u16*   maskb   = (u16*)(Smean + (size_t)NB * NN * NN);  // 8.4 MB (guarded)
    const bool useMB = ws_size >= (size_t)(2 * NB * NN * NN * 4 + NB * NC1 * NN * NL * 2);

    // scratch inside the Aout region (consumed before k_final5 writes it):
    u16*   xb    = (u16*)Aout;                          // 8.4 MB bf16 x
    float* Spart = Aout + (size_t)16777216;             // 4 partials x 16.8 MB

    hipLaunchKernelGGL(k_cvt, dim3((NB * NCX * NN * ND / 8) / 256), dim3(256), 0,
                       stream, x, xb);
    if (useMB)
        hipLaunchKernelGGL(k_cvt, dim3((NB * NC1 * NN * NL / 8) / 256), dim3(256), 0,
                           stream, mask, (u16*)maskb);
    hipLaunchKernelGGL(k_meanA, dim3((NB * NN * NN / 4) / 256), dim3(256), 0, stream,
                       A, meanA);
    hipLaunchKernelGGL(k_smean5, dim3(NN / 8, NB, NCG), dim3(512), 0, stream,
                       xb, Spart);
    hipLaunchKernelGGL(k_sred, dim3((NB * NN * NN / 4) / 256), dim3(256), 0, stream,
                       Spart, Smean);
    if (useMB)
        hipLaunchKernelGGL(k_final5<true>, dim3(NN / 8, NC1, NB), dim3(512), 0,
                           stream, mask, maskb, Smean, meanA, Aout, maskUpd);
    else
        hipLaunchKernelGGL(k_final5<false>, dim3(NN / 8, NC1, NB), dim3(512), 0,
                           stream, mask, maskb, Smean, meanA, Aout, maskUpd);
}

// Round 6
// 639.014 us; speedup vs baseline: 1.0631x; 1.0631x over previous
//
#include <hip/hip_runtime.h>
#include <math.h>

#define NB 4
#define NCX 16
#define NC1 16
#define NCA 8
#define NN 1024
#define ND 64
#define NL 64
#define NCG 4          // channel groups for k_smean partials
#define HSTRIDE 1028   // halfwords; 2056B row step -> 2-way (free) on 2B stores
                       // and on b64 reads; 8B-aligned

typedef __attribute__((ext_vector_type(8))) short bf16x8;
typedef __attribute__((ext_vector_type(4))) float f32x4;
typedef _Float16 h4 __attribute__((ext_vector_type(4)));
typedef unsigned short u16;
typedef unsigned int u32;
typedef unsigned long long u64;

// RNE float -> bf16 bits
__device__ __forceinline__ u16 f2b(float f) {
    u32 u = __float_as_uint(f);
    return (u16)((u + 0x7FFFu + ((u >> 16) & 1u)) >> 16);
}

// load 8 consecutive floats, convert to a bf16 MFMA fragment
__device__ __forceinline__ bf16x8 cvt8(const float* __restrict__ p) {
    float4 a = *(const float4*)p;
    float4 b = *(const float4*)(p + 4);
    bf16x8 r;
    r[0] = (short)f2b(a.x); r[1] = (short)f2b(a.y);
    r[2] = (short)f2b(a.z); r[3] = (short)f2b(a.w);
    r[4] = (short)f2b(b.x); r[5] = (short)f2b(b.y);
    r[6] = (short)f2b(b.z); r[7] = (short)f2b(b.w);
    return r;
}

__device__ __forceinline__ float sigm(float z) {
    return 1.0f / (1.0f + __expf(-z));
}

// ---------------------------------------------------------------------------
// K0: generic fp32 -> bf16 (8 elems/thread). Used for x->xb and mask->maskb.
// ---------------------------------------------------------------------------
__global__ __launch_bounds__(256) void k_cvt(const float* __restrict__ src,
                                             u16* __restrict__ dst) {
    int id = blockIdx.x * 256 + threadIdx.x;
    const float4* x4 = (const float4*)src;
    float4 a = x4[2 * id];
    float4 b = x4[2 * id + 1];
    union { u16 u[8]; uint4 v; } o;
    o.u[0] = f2b(a.x); o.u[1] = f2b(a.y); o.u[2] = f2b(a.z); o.u[3] = f2b(a.w);
    o.u[4] = f2b(b.x); o.u[5] = f2b(b.y); o.u[6] = f2b(b.z); o.u[7] = f2b(b.w);
    ((uint4*)dst)[id] = o.v;
}

// ---------------------------------------------------------------------------
// K1: meanA[b,i,j] = (1/8) * sum_c A[b,c,i,j]
// ---------------------------------------------------------------------------
__global__ __launch_bounds__(256) void k_meanA(const float* __restrict__ A,
                                               float* __restrict__ meanA) {
    int id = blockIdx.x * 256 + threadIdx.x;
    int b  = id >> 18;                         // N*N/4 = 262144
    int e  = id & 262143;
    const float4* A4 = (const float4*)A;
    float4 s = A4[(size_t)(b * NCA) * 262144 + e];
#pragma unroll
    for (int c = 1; c < NCA; ++c) {
        float4 v = A4[(size_t)(b * NCA + c) * 262144 + e];
        s.x += v.x; s.y += v.y; s.z += v.z; s.w += v.w;
    }
    s.x *= 0.125f; s.y *= 0.125f; s.z *= 0.125f; s.w *= 0.125f;
    ((float4*)meanA)[id] = s;
}

// ---------------------------------------------------------------------------
// K1b: T[b,row] = exact 5th-largest of meanA[b,row,:]. One wave per row.
// Any top-5 element of A_out = meanA + 0.02*sigmoid(..) has A_out >= T
// (pointwise A_out >= meanA -> 5th order stat dominates). 4096 waves, ~5us.
// ---------------------------------------------------------------------------
__global__ __launch_bounds__(512) void k_thresh(const float* __restrict__ meanA,
                                                float* __restrict__ T) {
    const int t = threadIdx.x;
    const int w = t >> 6;
    const int l = t & 63;
    const int row = blockIdx.x * 8 + w;          // [0, NB*NN)
    const float* Mp = meanA + (size_t)row * NN;
    float v[16];
#pragma unroll
    for (int u = 0; u < 4; ++u) {
        float4 q = *(const float4*)(Mp + 4 * l + 256 * u);
        v[4 * u + 0] = q.x; v[4 * u + 1] = q.y;
        v[4 * u + 2] = q.z; v[4 * u + 3] = q.w;
    }
    float bv = 0.f;
#pragma unroll
    for (int p = 0; p < 5; ++p) {
        bv = v[0];
        int bj = 4 * l;
#pragma unroll
        for (int k = 1; k < 16; ++k) {
            int j = 4 * l + 256 * (k >> 2) + (k & 3);
            if (v[k] > bv) { bv = v[k]; bj = j; }
        }
#pragma unroll
        for (int off = 32; off; off >>= 1) {
            float ov = __shfl_xor(bv, off, 64);
            int   oj = __shfl_xor(bj, off, 64);
            if (ov > bv || (ov == bv && oj < bj)) { bv = ov; bj = oj; }
        }
        const bool mine = ((bj & 255) >> 2) == l;
        const int  ck   = (bj >> 8) * 4 + (bj & 3);
#pragma unroll
        for (int k = 0; k < 16; ++k)
            v[k] = (mine && k == ck) ? -INFINITY : v[k];
    }
    if (l == 0) T[row] = bv;    // value of the 5th pass = 5th-largest
}

// ---------------------------------------------------------------------------
// K2: partial softmax-sums. 512-thread blocks, 16-row i-tile (NO wasted MFMA).
// Wave w computes cols [w*128,(w+1)*128) over all 16 rows (8 MFMA tile-pairs),
// then softmaxes rows 2w and 2w+1. fp16 logits in LDS (32.9 KB -> 3 blk/CU).
// Spart[cg][b][i][j] = sum_{c in group} softmax_j(x_i . x_j).
// ---------------------------------------------------------------------------
__global__ __launch_bounds__(512, 6) void k_smean6(const u16* __restrict__ xb,
                                                   float* __restrict__ Spart) {
    __shared__ _Float16 Lh[16 * HSTRIDE];   // 32.9 KB
    const int t  = threadIdx.x;
    const int w  = t >> 6;              // wave 0..7
    const int l  = t & 63;
    const int lm = l & 15;
    const int lq = l >> 4;
    const int i0 = blockIdx.x * 16;
    const int b  = blockIdx.y;
    const int cg = blockIdx.z;
    const int rb = lq * 4;              // C/D row base

    float mean[2][16];
#pragma unroll
    for (int s = 0; s < 2; ++s)
#pragma unroll
        for (int u = 0; u < 16; ++u) mean[s][u] = 0.f;

    const int arow = i0 + lm;

    for (int c = cg * 4; c < cg * 4 + 4; ++c) {
        const u16* Xc = xb + (size_t)(b * NCX + c) * NN * ND;
        bf16x8 a0 = *(const bf16x8*)(Xc + arow * ND + lq * 8);
        bf16x8 a1 = *(const bf16x8*)(Xc + arow * ND + 32 + lq * 8);
#pragma unroll
        for (int tt = 0; tt < 8; ++tt) {
            int j0 = w * 128 + tt * 16;
            const u16* Bp = Xc + (j0 + lm) * ND;
            bf16x8 b0 = *(const bf16x8*)(Bp + lq * 8);
            bf16x8 b1 = *(const bf16x8*)(Bp + 32 + lq * 8);
            f32x4 acc = {0.f, 0.f, 0.f, 0.f};
            acc = __builtin_amdgcn_mfma_f32_16x16x32_bf16(a0, b0, acc, 0, 0, 0);
            acc = __builtin_amdgcn_mfma_f32_16x16x32_bf16(a1, b1, acc, 0, 0, 0);
            int col = j0 + lm;
            Lh[(rb + 0) * HSTRIDE + col] = (_Float16)acc[0];
            Lh[(rb + 1) * HSTRIDE + col] = (_Float16)acc[1];
            Lh[(rb + 2) * HSTRIDE + col] = (_Float16)acc[2];
            Lh[(rb + 3) * HSTRIDE + col] = (_Float16)acc[3];
        }
        __syncthreads();
#pragma unroll
        for (int s = 0; s < 2; ++s) {   // rows 2w, 2w+1; lane owns cols 4l+256u+k
            const _Float16* Lp = &Lh[(2 * w + s) * HSTRIDE];
            float v[16];
#pragma unroll
            for (int u = 0; u < 4; ++u) {
                h4 q = *(const h4*)&Lp[4 * l + 256 * u];
                v[4 * u + 0] = (float)q[0]; v[4 * u + 1] = (float)q[1];
                v[4 * u + 2] = (float)q[2]; v[4 * u + 3] = (float)q[3];
            }
            float m = v[0];
#pragma unroll
            for (int u = 1; u < 16; ++u) m = fmaxf(m, v[u]);
#pragma unroll
            for (int off = 32; off; off >>= 1) m = fmaxf(m, __shfl_xor(m, off, 64));
            float sum = 0.f;
#pragma unroll
            for (int u = 0; u < 16; ++u) { v[u] = __expf(v[u] - m); sum += v[u]; }
#pragma unroll
            for (int off = 32; off; off >>= 1) sum += __shfl_xor(sum, off, 64);
            float r = 1.0f / sum;
#pragma unroll
            for (int u = 0; u < 16; ++u) mean[s][u] = fmaf(v[u], r, mean[s][u]);
        }
        __syncthreads();   // before next channel overwrites Lh
    }
#pragma unroll
    for (int s = 0; s < 2; ++s) {
        float* Sp = Spart + (((size_t)(cg * NB + b)) * NN + (i0 + 2 * w + s)) * NN;
#pragma unroll
        for (int u = 0; u < 4; ++u) {
            float4 o;
            o.x = mean[s][4 * u + 0]; o.y = mean[s][4 * u + 1];
            o.z = mean[s][4 * u + 2]; o.w = mean[s][4 * u + 3];
            *(float4*)(Sp + 4 * l + 256 * u) = o;
        }
    }
}

// ---------------------------------------------------------------------------
// K2b: Smean = (1/16) * (P0+P1+P2+P3)
// ---------------------------------------------------------------------------
__global__ __launch_bounds__(256) void k_sred(const float* __restrict__ Spart,
                                              float* __restrict__ Smean) {
    int id = blockIdx.x * 256 + threadIdx.x;   // float4 index over B*N*N/4
    int b  = id >> 18;
    int e  = id & 262143;
    const float4* P4 = (const float4*)Spart;
    float4 s = P4[(size_t)b * 262144 + e];
#pragma unroll
    for (int g = 1; g < NCG; ++g) {
        float4 v = P4[(size_t)(g * NB + b) * 262144 + e];
        s.x += v.x; s.y += v.y; s.z += v.z; s.w += v.w;
    }
    s.x *= 0.0625f; s.y *= 0.0625f; s.z *= 0.0625f; s.w *= 0.0625f;
    ((float4*)Smean)[id] = s;
}

// ---------------------------------------------------------------------------
// K3: mm via MFMA -> fp16 LDS -> per-wave-row epilogue (round-5 geometry,
// occupancy 85%). Top-5: candidate-count vs T (5th-largest meanA); if exactly
// 5 candidates (~80% of rows) the set IS the top-5 (max-gather is order/tie
// invariant) -> extract from ballot bits, no masked re-scans. Else verbatim
// 5-pass fallback.
// ---------------------------------------------------------------------------
template <bool FAST>
__global__ __launch_bounds__(512, 8) void k_final6(const float* __restrict__ mask,
                                                   const u16* __restrict__ maskb,
                                                   const float* __restrict__ Smean,
                                                   const float* __restrict__ meanA,
                                                   const float* __restrict__ T,
                                                   float* __restrict__ Aout,
                                                   float* __restrict__ maskUpd) {
    __shared__ _Float16 Lh[8 * HSTRIDE];   // 16.4 KB
    const int t  = threadIdx.x;
    const int w  = t >> 6;
    const int l  = t & 63;
    const int lm = l & 15;
    const int lq = l >> 4;
    const int i0 = blockIdx.x * 8;
    const int c1 = blockIdx.y;
    const int b  = blockIdx.z;
    const int rb = lq * 4;
    const int row = i0 + w;

    const float* mbase = mask + (size_t)(b * NC1 + c1) * NN * NL;
    const u16*   mbb   = maskb + (size_t)(b * NC1 + c1) * NN * NL;

    const int arow = min(i0 + lm, NN - 1);   // rows >= 8 computed, discarded
    bf16x8 a0, a1;
    if (FAST) {
        a0 = *(const bf16x8*)(mbb + arow * NL + lq * 8);
        a1 = *(const bf16x8*)(mbb + arow * NL + 32 + lq * 8);
    } else {
        a0 = cvt8(mbase + arow * NL + lq * 8);
        a1 = cvt8(mbase + arow * NL + 32 + lq * 8);
    }
#pragma unroll
    for (int tt = 0; tt < 8; ++tt) {
        int j0 = w * 128 + tt * 16;
        bf16x8 b0, b1;
        if (FAST) {
            const u16* Bp = mbb + (j0 + lm) * NL;
            b0 = *(const bf16x8*)(Bp + lq * 8);
            b1 = *(const bf16x8*)(Bp + 32 + lq * 8);
        } else {
            const float* Bp = mbase + (j0 + lm) * NL;
            b0 = cvt8(Bp + lq * 8);
            b1 = cvt8(Bp + 32 + lq * 8);
        }
        f32x4 acc = {0.f, 0.f, 0.f, 0.f};
        acc = __builtin_amdgcn_mfma_f32_16x16x32_bf16(a0, b0, acc, 0, 0, 0);
        acc = __builtin_amdgcn_mfma_f32_16x16x32_bf16(a1, b1, acc, 0, 0, 0);
        if (lq < 2) {
            int col = j0 + lm;
            Lh[(rb + 0) * HSTRIDE + col] = (_Float16)acc[0];
            Lh[(rb + 1) * HSTRIDE + col] = (_Float16)acc[1];
            Lh[(rb + 2) * HSTRIDE + col] = (_Float16)acc[2];
            Lh[(rb + 3) * HSTRIDE + col] = (_Float16)acc[3];
        }
    }
    __syncthreads();

    const _Float16* Lp = &Lh[w * HSTRIDE];
    const float* Sp = Smean + ((size_t)b * NN + row) * NN;
    const float* Mp = meanA + ((size_t)b * NN + row) * NN;
    float* Ap = Aout + ((size_t)(b * NC1 + c1) * NN + row) * NN;

    float lg[16];
#pragma unroll
    for (int u = 0; u < 4; ++u) {
        int j = 4 * l + 256 * u;
        h4 q = *(const h4*)&Lp[j];
        float4 S4 = *(const float4*)(Sp + j);
        float4 M4 = *(const float4*)(Mp + j);
        float4 o;
        o.x = M4.x + 0.02f * sigm(S4.x * (float)q[0] * 0.31622776601683794f);
        o.y = M4.y + 0.02f * sigm(S4.y * (float)q[1] * 0.31622776601683794f);
        o.z = M4.z + 0.02f * sigm(S4.z * (float)q[2] * 0.31622776601683794f);
        o.w = M4.w + 0.02f * sigm(S4.w * (float)q[3] * 0.31622776601683794f);
        *(float4*)(Ap + j) = o;
        lg[4 * u + 0] = o.x; lg[4 * u + 1] = o.y;
        lg[4 * u + 2] = o.z; lg[4 * u + 3] = o.w;
    }

    float mx = -INFINITY;
    bool done = false;
    if (FAST) {
        const float Tr = T[(size_t)b * NN + row];   // wave-uniform
        int m = 0;
#pragma unroll
        for (int k = 0; k < 16; ++k)
            m += __popcll(__ballot(lg[k] >= Tr));
        if (m == 5) {                                // candidate set == top-5 set
#pragma unroll
            for (int k = 0; k < 16; ++k) {
                u64 bk = __ballot(lg[k] >= Tr);
                while (bk) {
                    int src = __ffsll((unsigned long long)bk) - 1;
                    bk &= bk - 1;
                    int idx = 4 * src + 256 * (k >> 2) + (k & 3);
                    mx = fmaxf(mx, mbase[(size_t)idx * NL + l]);
                }
            }
            done = true;
        }
    }
    if (!done) {
        // verbatim 5-pass argmax (tie -> lowest index), then gather
        int idxs[5];
#pragma unroll
        for (int p = 0; p < 5; ++p) {
            float bv = lg[0];
            int   bj = 4 * l;
#pragma unroll
            for (int k = 1; k < 16; ++k) {
                int j = 4 * l + 256 * (k >> 2) + (k & 3);
                if (lg[k] > bv) { bv = lg[k]; bj = j; }
            }
#pragma unroll
            for (int off = 32; off; off >>= 1) {
                float ov = __shfl_xor(bv, off, 64);
                int   oj = __shfl_xor(bj, off, 64);
                if (ov > bv || (ov == bv && oj < bj)) { bv = ov; bj = oj; }
            }
            idxs[p] = bj;
            const bool mine = ((bj & 255) >> 2) == l;
            const int  ck   = (bj >> 8) * 4 + (bj & 3);
#pragma unroll
            for (int k = 0; k < 16; ++k)
                lg[k] = (mine && k == ck) ? -INFINITY : lg[k];
        }
        mx = mbase[(size_t)idxs[0] * NL + l];
#pragma unroll
        for (int p = 1; p < 5; ++p)
            mx = fmaxf(mx, mbase[(size_t)idxs[p] * NL + l]);
    }
    maskUpd[((size_t)(b * NC1 + c1) * NN + row) * NL + l] = mx;
}

// ---------------------------------------------------------------------------
extern "C" void kernel_launch(void* const* d_in, const int* in_sizes, int n_in,
                              void* d_out, int out_size, void* d_ws, size_t ws_size,
                              hipStream_t stream) {
    const float* x    = (const float*)d_in[0];
    const float* A    = (const float*)d_in[1];
    const float* mask = (const float*)d_in[2];
    float* out     = (float*)d_out;
    float* Aout    = out;                                   // (B,C1,N,N)
    float* maskUpd = out + (size_t)NB * NC1 * NN * NN;      // (B,C1,N,L)
    float* meanA   = (float*)d_ws;                          // (B,N,N)  16.8 MB
    float* Smean   = meanA + (size_t)NB * NN * NN;          // (B,N,N)  16.8 MB
    u16*   maskb   = (u16*)(Smean + (size_t)NB * NN * NN);  // 8.4 MB
    float* T       = (float*)(maskb + (size_t)NB * NC1 * NN * NL);  // 16 KB
    const size_t need = (size_t)2 * NB * NN * NN * 4
                      + (size_t)NB * NC1 * NN * NL * 2
                      + (size_t)NB * NN * 4;
    const bool fast = ws_size >= need;

    // scratch inside the Aout region (consumed before k_final6 writes it):
    u16*   xb    = (u16*)Aout;                          // 8.4 MB bf16 x
    float* Spart = Aout + (size_t)16777216;             // 4 partials x 16.8 MB

    hipLaunchKernelGGL(k_cvt, dim3((NB * NCX * NN * ND / 8) / 256), dim3(256), 0,
                       stream, x, xb);
    if (fast)
        hipLaunchKernelGGL(k_cvt, dim3((NB * NC1 * NN * NL / 8) / 256), dim3(256), 0,
                           stream, mask, (u16*)maskb);
    hipLaunchKernelGGL(k_meanA, dim3((NB * NN * NN / 4) / 256), dim3(256), 0, stream,
                       A, meanA);
    if (fast)
        hipLaunchKernelGGL(k_thresh, dim3(NB * NN / 8), dim3(512), 0, stream,
                           meanA, T);
    hipLaunchKernelGGL(k_smean6, dim3(NN / 16, NB, NCG), dim3(512), 0, stream,
                       xb, Spart);
    hipLaunchKernelGGL(k_sred, dim3((NB * NN * NN / 4) / 256), dim3(256), 0, stream,
                       Spart, Smean);
    if (fast)
        hipLaunchKernelGGL(k_final6<true>, dim3(NN / 8, NC1, NB), dim3(512), 0,
                           stream, mask, maskb, Smean, meanA, T, Aout, maskUpd);
    else
        hipLaunchKernelGGL(k_final6<false>, dim3(NN / 8, NC1, NB), dim3(512), 0,
                           stream, mask, maskb, Smean, meanA, T, Aout, maskUpd);
}